// Round 7
// baseline (1042.928 us; speedup 1.0000x reference)
//
#include <hip/hip_runtime.h>

typedef short s16x8 __attribute__((ext_vector_type(8)));
typedef short s16x4 __attribute__((ext_vector_type(4)));
typedef float f32x4 __attribute__((ext_vector_type(4)));
typedef unsigned int u32;
typedef unsigned short u16;

#define NT 512
#define DD 64
#define BB 8
#define NTH 512

#define CHUNK 1024

// ---------- T=4 superstep recurrent kernel LDS ----------
#define TCH 4096            // per-layer chunk per parity: 4 slots x 1024 u16
#define P3 (5*TCH)          // 20480 u16
#define FR3 (2*P3)          // 40960 u16 = 81920 B
#define XST 6144            // f32 per parity for L4 x-part stage (4t x 2jt x 3g x 256)
#define LDS3_BYTES (FR3*2 + 2*XST*4)   // 81920 + 49152 = 131072
#define NSUP 134            // 128 + 6 pipeline stages

// ---------- fallback (round-3) LDS ----------
#define PSTRIDE (7*CHUNK)
#define XIN0 0
#define H0C (2*CHUNK)
#define H1C (3*CHUNK)
#define H2C (4*CHUNK)
#define H3C (5*CHUNK)
#define H4C (6*CHUNK)
#define FRTOT (2*PSTRIDE)
#define NSTEP_FB 517

#define MFMA16(A,B,C) __builtin_amdgcn_mfma_f32_16x16x32_bf16(A,B,C,0,0,0)

__device__ __forceinline__ float sigf(float x){ return 1.0f/(1.0f+__expf(-x)); }
__device__ __forceinline__ float tanhf2(float x){ return 2.0f/(1.0f+__expf(-2.0f*x)) - 1.0f; }

__device__ __forceinline__ u16 f2bf(float f) {
  u32 u = __builtin_bit_cast(u32, f);
  return (u16)((u + 0x7fffu + ((u >> 16) & 1u)) >> 16);
}
__device__ __forceinline__ float bf2f(u16 h) {
  u32 u = ((u32)h) << 16;
  return __builtin_bit_cast(float, u);
}

// barrier WITHOUT the vmcnt(0) drain: LDS visibility only (global ops drain at use)
__device__ __forceinline__ void soft_barrier() {
  asm volatile("s_waitcnt lgkmcnt(0)" ::: "memory");
  __builtin_amdgcn_s_barrier();
  asm volatile("" ::: "memory");
}

__device__ __forceinline__ u32 cvtpk_bf16(float a, float b) {
  u32 r;
  asm("v_cvt_pk_bf16_f32 %0, %1, %2" : "=v"(r) : "v"(a), "v"(b));
  return r;
}

// A-fragment: lane holds A[row0 + (lane&15)][kbase + (lane>>4)*8 + e], zero-padded.
__device__ __forceinline__ void load_wfrag(const float* __restrict__ W, int row0, int nrow, int din,
                                           int kbase, int lane, s16x8& hi, s16x8& lo)
{
  const int m = lane & 15, kb = lane >> 4;
#pragma unroll
  for (int e = 0; e < 8; ++e) {
    int k = kbase + kb*8 + e;
    float v = (m < nrow && k < din) ? W[(size_t)(row0 + m)*din + k] : 0.0f;
    u16 h = f2bf(v);
    hi[e] = (short)h;
    lo[e] = (short)f2bf(v - bf2f(h));
  }
}

// B-fragment read: lane reads B[k=(lane>>4)*8+e][col=lane&15] (hi at +0, lo at +128)
__device__ __forceinline__ void read_b(const u16* base, int lane, s16x8& hi, s16x8& lo)
{
  const int off = ((lane >> 4) << 8) + ((lane & 15) << 3);
  hi = *(const s16x8*)(base + off);
  lo = *(const s16x8*)(base + off + 128);
}

// 3-MFMA hi/lo product group
__device__ __forceinline__ void g3(const s16x8& Ah, const s16x8& Al,
                                   const s16x8& bh, const s16x8& bl, f32x4& acc)
{
  acc = MFMA16(Ah, bh, acc);
  acc = MFMA16(Ah, bl, acc);
  acc = MFMA16(Al, bh, acc);
}

// gate combine + h write (cvt_pk packing); writes lanes bb<8, j = jbase + q*4 (+0..3)
__device__ __forceinline__ void combine_write2(
    f32x4 aR, f32x4 aZ, f32x4 aNi, f32x4 aNh,
    float (&hprev)[4], u16* hdst_base, int jbase, int nrow, int lane)
{
  const int bb = lane & 15, q = lane >> 4;
  float hv[4];
#pragma unroll
  for (int i = 0; i < 4; ++i) {
    float rr = sigf(aR[i]);
    float zz = sigf(aZ[i]);
    float nn = tanhf2(aNi[i] + rr*aNh[i]);
    hv[i] = (1.0f - zz)*nn + zz*hprev[i];
    hprev[i] = hv[i];
  }
  if (bb < 8 && q*4 < nrow) {
    const int j = jbase + q*4;
    u16* dst = hdst_base + ((j >> 3) << 8) + bb*8 + (j & 7);
    u32 p01 = cvtpk_bf16(hv[0], hv[1]);
    u32 p23 = cvtpk_bf16(hv[2], hv[3]);
    float h0 = __builtin_bit_cast(float, p01 << 16);
    float h1 = __builtin_bit_cast(float, p01 & 0xffff0000u);
    float h2 = __builtin_bit_cast(float, p23 << 16);
    float h3 = __builtin_bit_cast(float, p23 & 0xffff0000u);
    u32 q01 = cvtpk_bf16(hv[0]-h0, hv[1]-h1);
    u32 q23 = cvtpk_bf16(hv[2]-h2, hv[3]-h3);
    uint2 hp_; hp_.x = p01; hp_.y = p23;
    uint2 lp_; lp_.x = q01; lp_.y = q23;
    *(uint2*)dst = hp_;
    *(uint2*)(dst + 128) = lp_;
  }
}

// =====================================================================
// Phase 1: gi0[b][t][96] = Wih0 @ x_imp(b,t) + bih0 (+bhh0 for r,z rows)
// =====================================================================
__global__ __launch_bounds__(256)
void gi0_gemm(const float* __restrict__ X, const float* __restrict__ M, const float* __restrict__ L,
              const float* __restrict__ wih0, const float* __restrict__ bih0,
              const float* __restrict__ bhh0,
              float* __restrict__ gi)
{
  __shared__ u32 xs[128*65];
  const int tid = threadIdx.x;
  const int wv = tid >> 6, lane = tid & 63;
  const int q = lane >> 4;
  const int b = blockIdx.x >> 2;
  const int t0 = (blockIdx.x & 3) * 128;
  const size_t base = ((size_t)b*NT + t0)*DD;

  for (int i = tid; i < 128*64; i += 256) {
    float x = X[base+i], m = M[base+i], l = L[base+i];
    float v = x*m + l*(1.0f - m);
    u16 h = f2bf(v);
    u16 lo2 = f2bf(v - bf2f(h));
    const int t = i >> 6, d = i & 63;
    xs[t*65 + d] = (u32)h | ((u32)lo2 << 16);
  }

  s16x8 Ah[6][2], Al[6][2];
  f32x4 cb[6];
#pragma unroll
  for (int tile = 0; tile < 6; ++tile) {
#pragma unroll
    for (int c = 0; c < 2; ++c)
      load_wfrag(wih0, tile*16, 16, 64, c*32, lane, Ah[tile][c], Al[tile][c]);
#pragma unroll
    for (int i = 0; i < 4; ++i) {
      int row = tile*16 + q*4 + i;
      float bv = bih0[row];
      if (tile < 4) bv += bhh0[row];
      cb[tile][i] = bv;
    }
  }
  __syncthreads();

#pragma unroll
  for (int g2 = 0; g2 < 2; ++g2) {
    const int tloc = g2*64 + wv*16 + (lane & 15);
    s16x8 Bh[2], Bl[2];
#pragma unroll
    for (int c = 0; c < 2; ++c) {
      const u32* p = &xs[tloc*65 + c*32 + q*8];
#pragma unroll
      for (int e = 0; e < 8; ++e) {
        u32 v = p[e];
        Bh[c][e] = (short)(v & 0xffffu);
        Bl[c][e] = (short)(v >> 16);
      }
    }
    float* gp = gi + ((size_t)b*NT + t0 + tloc)*96 + q*4;
#pragma unroll
    for (int tile = 0; tile < 6; ++tile) {
      f32x4 acc = cb[tile];
#pragma unroll
      for (int c = 0; c < 2; ++c) {
        acc = MFMA16(Ah[tile][c], Bh[c], acc);
        acc = MFMA16(Ah[tile][c], Bl[c], acc);
        acc = MFMA16(Al[tile][c], Bh[c], acc);
      }
      *(f32x4*)(gp + tile*16) = acc;
    }
  }
}

// =====================================================================
// Phase 2: T=4 superstep recurrent kernel. One wave owns a full layer;
// within a superstep the recurrence stays wave-local (no barrier).
// Chunks (per parity): 0=H0,1=H1,2=H2,3=H3,4=H4; each 4 slots of 1024 u16.
// =====================================================================
__device__ void wv_l0_t4(const float* __restrict__ whh0, const float* __restrict__ bhh0,
                         const float* __restrict__ gi, u16* FR, int b0, int lane)
{
  s16x8 Ahh[2][3], Ahl[2][3];
#pragma unroll
  for (int jt = 0; jt < 2; ++jt)
#pragma unroll
    for (int g = 0; g < 3; ++g)
      load_wfrag(whh0, g*32 + jt*16, 16, 32, 0, lane, Ahh[jt][g], Ahl[jt][g]);
  const int q = lane >> 4;
  f32x4 cNh[2];
#pragma unroll
  for (int jt = 0; jt < 2; ++jt)
#pragma unroll
    for (int i = 0; i < 4; ++i) cNh[jt][i] = bhh0[64 + jt*16 + q*4 + i];
  float hp[2][4] = {};
  const float* gp = gi + (size_t)(b0 + (lane & 7)) * ((size_t)NT*96) + q*4;

  for (int S = 0; S < NSUP; ++S) {
    const int par = S & 1, rp = par ^ 1;
    if (S < 128) {
      const int tb = 4*S;
      f32x4 g_[4][2][3];
#pragma unroll
      for (int t = 0; t < 4; ++t)
#pragma unroll
        for (int jt = 0; jt < 2; ++jt) {
          const float* p = gp + (size_t)(tb + t)*96 + jt*16;
          g_[t][jt][0] = *(const f32x4*)p;         // r (bih+bhh folded)
          g_[t][jt][1] = *(const f32x4*)(p + 32);  // z (bih+bhh folded)
          g_[t][jt][2] = *(const f32x4*)(p + 64);  // n (bih folded)
        }
      const u16* RH = FR + rp*P3 + 0*TCH;
      u16* WH = FR + par*P3 + 0*TCH;
      s16x8 hh_, hl_;
      read_b(RH + 3*1024, lane, hh_, hl_);
#pragma unroll
      for (int t = 0; t < 4; ++t) {
#pragma unroll
        for (int jt = 0; jt < 2; ++jt) {
          f32x4 hR = {0.f,0.f,0.f,0.f}, hZ = {0.f,0.f,0.f,0.f}, aNh = cNh[jt];
          g3(Ahh[jt][0], Ahl[jt][0], hh_, hl_, hR);
          g3(Ahh[jt][1], Ahl[jt][1], hh_, hl_, hZ);
          g3(Ahh[jt][2], Ahl[jt][2], hh_, hl_, aNh);
          f32x4 aR = hR + g_[t][jt][0];
          f32x4 aZ = hZ + g_[t][jt][1];
          combine_write2(aR, aZ, g_[t][jt][2], aNh, hp[jt], WH + t*1024, jt*16, 16, lane);
        }
        if (t < 3) read_b(WH + t*1024, lane, hh_, hl_);
      }
    }
    soft_barrier();
  }
}

template<int DIN, int DH>
__device__ void wv_mid4(const float* __restrict__ Wih, const float* __restrict__ Whh,
                        const float* __restrict__ bih, const float* __restrict__ bhh,
                        int cx, int ch, int Sf, u16* FR, int lane)
{
  constexpr int nrow = DH < 16 ? DH : 16;
  s16x8 Axh[3], Axl[3], Ahh[3], Ahl[3];
#pragma unroll
  for (int g = 0; g < 3; ++g) {
    load_wfrag(Wih, g*DH, nrow, DIN, 0, lane, Axh[g], Axl[g]);
    load_wfrag(Whh, g*DH, nrow, DH, 0, lane, Ahh[g], Ahl[g]);
  }
  const int q = lane >> 4;
  f32x4 cR, cZ, cNi, cNh;
#pragma unroll
  for (int i = 0; i < 4; ++i) {
    int j = q*4 + i;
    bool jr = j < nrow;
    cR[i]  = jr ? bih[j] + bhh[j] : 0.f;
    cZ[i]  = jr ? bih[DH+j] + bhh[DH+j] : 0.f;
    cNi[i] = jr ? bih[2*DH+j] : 0.f;
    cNh[i] = jr ? bhh[2*DH+j] : 0.f;
  }
  float hp[4] = {0.f,0.f,0.f,0.f};

  for (int S = 0; S < NSUP; ++S) {
    const int par = S & 1, rp = par ^ 1;
    if (S >= Sf && S < Sf + 128) {
      const u16* RX = FR + rp*P3 + cx*TCH;
      const u16* RH = FR + rp*P3 + ch*TCH;
      u16* WH = FR + par*P3 + ch*TCH;
      s16x8 xh[4], xl[4];
#pragma unroll
      for (int t = 0; t < 4; ++t) read_b(RX + t*1024, lane, xh[t], xl[t]);
      f32x4 aR[4], aZ[4], aNi[4], aNh[4];
#pragma unroll
      for (int t = 0; t < 4; ++t) {
        aR[t] = cR; aZ[t] = cZ; aNi[t] = cNi; aNh[t] = cNh;
        g3(Axh[0], Axl[0], xh[t], xl[t], aR[t]);
        g3(Axh[1], Axl[1], xh[t], xl[t], aZ[t]);
        g3(Axh[2], Axl[2], xh[t], xl[t], aNi[t]);
      }
      s16x8 hh_, hl_;
      read_b(RH + 3*1024, lane, hh_, hl_);
#pragma unroll
      for (int t = 0; t < 4; ++t) {
        g3(Ahh[0], Ahl[0], hh_, hl_, aR[t]);
        g3(Ahh[1], Ahl[1], hh_, hl_, aZ[t]);
        g3(Ahh[2], Ahl[2], hh_, hl_, aNh[t]);
        combine_write2(aR[t], aZ[t], aNi[t], aNh[t], hp, WH + t*1024, 0, nrow, lane);
        if (t < 3) read_b(WH + t*1024, lane, hh_, hl_);
      }
    }
    soft_barrier();
  }
}

// L4 x-parts (no recurrence): h3 -> XS f32 stage, one superstep ahead of L4h.
__device__ void wv_l4x(const float* __restrict__ wih4, const float* __restrict__ bih4,
                       const float* __restrict__ bhh4,
                       u16* FR, float* XS, int lane)
{
  s16x8 Axh[2][3], Axl[2][3];
#pragma unroll
  for (int jt = 0; jt < 2; ++jt)
#pragma unroll
    for (int g = 0; g < 3; ++g)
      load_wfrag(wih4, g*32 + jt*16, 16, 16, 0, lane, Axh[jt][g], Axl[jt][g]);
  const int q = lane >> 4;
  f32x4 cR[2], cZ[2], cNi[2];
#pragma unroll
  for (int jt = 0; jt < 2; ++jt)
#pragma unroll
    for (int i = 0; i < 4; ++i) {
      int j = jt*16 + q*4 + i;
      cR[jt][i]  = bih4[j] + bhh4[j];
      cZ[jt][i]  = bih4[32+j] + bhh4[32+j];
      cNi[jt][i] = bih4[64+j];
    }
  for (int S = 0; S < NSUP; ++S) {
    const int par = S & 1, rp = par ^ 1;
    if (S >= 4 && S < 4 + 128) {
      const u16* RX = FR + rp*P3 + 3*TCH;   // h3
      float* XW = XS + par*XST;
#pragma unroll
      for (int t = 0; t < 4; ++t) {
        s16x8 bh_, bl_;
        read_b(RX + t*1024, lane, bh_, bl_);
#pragma unroll
        for (int jt = 0; jt < 2; ++jt) {
          f32x4 aR = cR[jt], aZ = cZ[jt], aNi = cNi[jt];
          g3(Axh[jt][0], Axl[jt][0], bh_, bl_, aR);
          g3(Axh[jt][1], Axl[jt][1], bh_, bl_, aZ);
          g3(Axh[jt][2], Axl[jt][2], bh_, bl_, aNi);
          float* w = XW + t*1536 + jt*768 + lane*4;
          *(f32x4*)(w)       = aR;
          *(f32x4*)(w + 256) = aZ;
          *(f32x4*)(w + 512) = aNi;
        }
      }
    }
    soft_barrier();
  }
}

// L4 recurrent part: XS (x-parts) + Whh4·h4 -> combine -> H4
__device__ void wv_l4h(const float* __restrict__ whh4, const float* __restrict__ bhh4,
                       u16* FR, const float* XS, int lane)
{
  s16x8 Ahh[2][3], Ahl[2][3];
#pragma unroll
  for (int jt = 0; jt < 2; ++jt)
#pragma unroll
    for (int g = 0; g < 3; ++g)
      load_wfrag(whh4, g*32 + jt*16, 16, 32, 0, lane, Ahh[jt][g], Ahl[jt][g]);
  const int q = lane >> 4;
  f32x4 cNh[2];
#pragma unroll
  for (int jt = 0; jt < 2; ++jt)
#pragma unroll
    for (int i = 0; i < 4; ++i) cNh[jt][i] = bhh4[64 + jt*16 + q*4 + i];
  float hp[2][4] = {};

  for (int S = 0; S < NSUP; ++S) {
    const int par = S & 1, rp = par ^ 1;
    if (S >= 5 && S < 5 + 128) {
      const float* XR = XS + rp*XST;
      const u16* RH = FR + rp*P3 + 4*TCH;
      u16* WH = FR + par*P3 + 4*TCH;
      s16x8 hh_, hl_;
      read_b(RH + 3*1024, lane, hh_, hl_);
#pragma unroll
      for (int t = 0; t < 4; ++t) {
#pragma unroll
        for (int jt = 0; jt < 2; ++jt) {
          const float* r = XR + t*1536 + jt*768 + lane*4;
          f32x4 aR  = *(const f32x4*)r;
          f32x4 aZ  = *(const f32x4*)(r + 256);
          f32x4 aNi = *(const f32x4*)(r + 512);
          f32x4 aNh = cNh[jt];
          g3(Ahh[jt][0], Ahl[jt][0], hh_, hl_, aR);
          g3(Ahh[jt][1], Ahl[jt][1], hh_, hl_, aZ);
          g3(Ahh[jt][2], Ahl[jt][2], hh_, hl_, aNh);
          combine_write2(aR, aZ, aNi, aNh, hp[jt], WH + t*1024, jt*16, 16, lane);
        }
        if (t < 3) read_b(WH + t*1024, lane, hh_, hl_);
      }
    }
    soft_barrier();
  }
}

// OUT: half=0 -> d 0..31, half=1 -> d 32..63; all 4 timesteps; direct C-frag stores
__device__ void wv_out4(const float* __restrict__ OW, const float* __restrict__ OBb,
                        u16* FR, float* __restrict__ out, int b0, int half, int lane)
{
  s16x8 Oh[2], Ol[2];
  f32x4 cO[2];
  const int q = lane >> 4, bb = lane & 15;
#pragma unroll
  for (int k = 0; k < 2; ++k) {
    int tile = half*2 + k;
    load_wfrag(OW, tile*16, 16, 32, 0, lane, Oh[k], Ol[k]);
#pragma unroll
    for (int i = 0; i < 4; ++i) cO[k][i] = OBb[tile*16 + q*4 + i];
  }
  float* ob = out + ((size_t)(b0 + (bb & 7))*NT)*DD + half*32 + q*4;

  for (int S = 0; S < NSUP; ++S) {
    const int par = S & 1, rp = par ^ 1;
    if (S >= 6) {
      const u16* RH = FR + rp*P3 + 4*TCH;
      const int tbq = 4*(S - 6);
#pragma unroll
      for (int t = 0; t < 4; ++t) {
        s16x8 bh_, bl_;
        read_b(RH + t*1024, lane, bh_, bl_);
        float* op = ob + (size_t)(tbq + t)*DD;
#pragma unroll
        for (int k = 0; k < 2; ++k) {
          f32x4 a_ = cO[k];
          a_ = MFMA16(Oh[k], bh_, a_); a_ = MFMA16(Oh[k], bl_, a_); a_ = MFMA16(Ol[k], bh_, a_);
          if (bb < 8) *(f32x4*)(op + k*16) = a_;
        }
      }
    }
    soft_barrier();
  }
}

__global__ __launch_bounds__(NTH, 1)
void gru_rec_t4(const float* __restrict__ gi,
                const float* __restrict__ whh0, const float* __restrict__ bhh0,
                const float* __restrict__ wih1, const float* __restrict__ whh1, const float* __restrict__ bih1, const float* __restrict__ bhh1,
                const float* __restrict__ wih2, const float* __restrict__ whh2, const float* __restrict__ bih2, const float* __restrict__ bhh2,
                const float* __restrict__ wih3, const float* __restrict__ whh3, const float* __restrict__ bih3, const float* __restrict__ bhh3,
                const float* __restrict__ wih4, const float* __restrict__ whh4, const float* __restrict__ bih4, const float* __restrict__ bhh4,
                const float* __restrict__ out_w, const float* __restrict__ out_b,
                float* __restrict__ out)
{
  extern __shared__ __align__(16) u16 smem_u16[];
  u16* FR = smem_u16;
  float* XS = (float*)(smem_u16 + FR3);
  const int tid = threadIdx.x;
  const int w = tid >> 6, lane = tid & 63;
  const int b0 = blockIdx.x * BB;

  for (int i = tid; i < FR3; i += NTH) FR[i] = 0;
  for (int i = tid; i < 2*XST; i += NTH) XS[i] = 0.f;
  __syncthreads();

  if (w == 0)      wv_l0_t4(whh0, bhh0, gi, FR, b0, lane);
  else if (w == 1) wv_mid4<32,16>(wih1, whh1, bih1, bhh1, 0, 1, 1, FR, lane);
  else if (w == 2) wv_mid4<16, 8>(wih2, whh2, bih2, bhh2, 1, 2, 2, FR, lane);
  else if (w == 3) wv_mid4< 8,16>(wih3, whh3, bih3, bhh3, 2, 3, 3, FR, lane);
  else if (w == 4) wv_l4x(wih4, bih4, bhh4, FR, XS, lane);
  else if (w == 5) wv_l4h(whh4, bhh4, FR, XS, lane);
  else if (w == 6) wv_out4(out_w, out_b, FR, out, b0, 0, lane);
  else             wv_out4(out_w, out_b, FR, out, b0, 1, lane);
}

// =====================================================================
// Fallback: round-3 fused kernel (used only if ws_size is too small)
// =====================================================================
__device__ __forceinline__ void combine_write(
    f32x4 aR, f32x4 aZ, f32x4 aNi, f32x4 aNh,
    float (&hprev)[4], u16* hdst_base, int jbase, int nrow, int lane)
{
  const int bb = lane & 15, q = lane >> 4;
  float hv[4];
#pragma unroll
  for (int i = 0; i < 4; ++i) {
    float rr = sigf(aR[i]);
    float zz = sigf(aZ[i]);
    float nn = tanhf2(aNi[i] + rr*aNh[i]);
    hv[i] = (1.0f - zz)*nn + zz*hprev[i];
    hprev[i] = hv[i];
  }
  if (bb < 8 && q*4 < nrow) {
    const int j = jbase + q*4;
    const int kb = j >> 3, e = j & 7;
    s16x4 hh, ll;
#pragma unroll
    for (int i = 0; i < 4; ++i) {
      u16 h = f2bf(hv[i]);
      hh[i] = (short)h;
      ll[i] = (short)f2bf(hv[i] - bf2f(h));
    }
    u16* dst = hdst_base + kb*256 + bb*8 + e;
    *(s16x4*)dst = hh;
    *(s16x4*)(dst + 128) = ll;
  }
}

__device__ __forceinline__ void write_x(u16* FRu, int par, int w, int lane, float v)
{
  const int d = lane;
  const int chunk = d >> 5, kb = (d >> 3) & 3, e = d & 7;
  u16 h = f2bf(v);
  u16 l2 = f2bf(v - bf2f(h));
  u16* p = FRu + par*PSTRIDE + XIN0 + chunk*CHUNK + kb*256 + w*8 + e;
  p[0] = h; p[128] = l2;
}

template<int DIN, int DH, int NXC>
__device__ __forceinline__ void wave_gru_fb(
    const float* __restrict__ Wih, const float* __restrict__ Whh,
    const float* __restrict__ bih, const float* __restrict__ bhh,
    int jbase, int xc, int hc, int s0, int s1,
    u16* FRu, float* OST,
    const float* __restrict__ X, const float* __restrict__ Mm, const float* __restrict__ Ll,
    float* __restrict__ out, int b0, int w, int lane)
{
  const int nrow = (DH - jbase) < 16 ? (DH - jbase) : 16;
  s16x8 Axh[3][NXC], Axl[3][NXC], Ahh[3], Ahl[3];
#pragma unroll
  for (int g = 0; g < 3; ++g) {
#pragma unroll
    for (int c = 0; c < NXC; ++c)
      load_wfrag(Wih, g*DH + jbase, nrow, DIN, c*32, lane, Axh[g][c], Axl[g][c]);
    load_wfrag(Whh, g*DH + jbase, nrow, DH, 0, lane, Ahh[g], Ahl[g]);
  }
  f32x4 cR, cZ, cNi, cNh;
  {
    const int q = lane >> 4;
#pragma unroll
    for (int i = 0; i < 4; ++i) {
      int lr = q*4 + i;
      int j = jbase + lr;
      bool jr = lr < nrow;
      cR[i]  = jr ? bih[j] + bhh[j] : 0.f;
      cZ[i]  = jr ? bih[DH+j] + bhh[DH+j] : 0.f;
      cNi[i] = jr ? bih[2*DH+j] : 0.f;
      cNh[i] = jr ? bhh[2*DH+j] : 0.f;
    }
  }
  float hprev[4] = {0.f, 0.f, 0.f, 0.f};

  const size_t gbase = ((size_t)(b0 + w))*((size_t)NT*DD) + lane;
  float rx = X[gbase], rm = Mm[gbase], rl = Ll[gbase];
  write_x(FRu, 1, w, lane, rx*rm + rl*(1.0f - rm));
  rx = X[gbase + DD]; rm = Mm[gbase + DD]; rl = Ll[gbase + DD];
  __syncthreads();

  for (int s = 0; s < NSTEP_FB; ++s) {
    const int par = s & 1, rp = par ^ 1;
    float nx = 0.f, nm = 0.f, nl = 0.f;
    if (s <= 509) {
      size_t g = gbase + (size_t)(s+2)*DD;
      nx = X[g]; nm = Mm[g]; nl = Ll[g];
    }
    f32x4 aR = cR, aZ = cZ, aNi = cNi, aNh = cNh;
    const bool run = (s >= s0) && (s <= s1);
    if (run) {
      const u16* RB = FRu + rp*PSTRIDE;
      s16x8 bh_, bl_;
#pragma unroll
      for (int c = 0; c < NXC; ++c) {
        read_b(RB + xc + c*CHUNK, lane, bh_, bl_);
        aR  = MFMA16(Axh[0][c], bh_, aR);  aR  = MFMA16(Axh[0][c], bl_, aR);  aR  = MFMA16(Axl[0][c], bh_, aR);
        aZ  = MFMA16(Axh[1][c], bh_, aZ);  aZ  = MFMA16(Axh[1][c], bl_, aZ);  aZ  = MFMA16(Axl[1][c], bh_, aZ);
        aNi = MFMA16(Axh[2][c], bh_, aNi); aNi = MFMA16(Axh[2][c], bl_, aNi); aNi = MFMA16(Axl[2][c], bh_, aNi);
      }
      read_b(RB + hc, lane, bh_, bl_);
      aR  = MFMA16(Ahh[0], bh_, aR);  aR  = MFMA16(Ahh[0], bl_, aR);  aR  = MFMA16(Ahl[0], bh_, aR);
      aZ  = MFMA16(Ahh[1], bh_, aZ);  aZ  = MFMA16(Ahh[1], bl_, aZ);  aZ  = MFMA16(Ahl[1], bh_, aZ);
      aNh = MFMA16(Ahh[2], bh_, aNh); aNh = MFMA16(Ahh[2], bl_, aNh); aNh = MFMA16(Ahl[2], bh_, aNh);
    }
    __syncthreads();

    if (run)
      combine_write(aR, aZ, aNi, aNh, hprev, FRu + par*PSTRIDE + hc, jbase, nrow, lane);
    if (s >= 5)
      out[((size_t)(b0 + w)*NT + (s-5))*DD + lane] = OST[w*65 + lane];
    if (s <= 510) write_x(FRu, par, w, lane, rx*rm + rl*(1.0f - rm));
    rx = nx; rm = nm; rl = nl;
    __syncthreads();
  }
}

__device__ __forceinline__ void wave_out_fb(
    const float* __restrict__ OW, const float* __restrict__ OBb,
    u16* FRu, float* OST,
    const float* __restrict__ X, const float* __restrict__ Mm, const float* __restrict__ Ll,
    float* __restrict__ out, int b0, int w, int lane)
{
  s16x8 Oh[4], Ol[4];
  f32x4 cO[4];
#pragma unroll
  for (int t4 = 0; t4 < 4; ++t4) {
    load_wfrag(OW, t4*16, 16, 32, 0, lane, Oh[t4], Ol[t4]);
#pragma unroll
    for (int i = 0; i < 4; ++i) cO[t4][i] = OBb[t4*16 + (lane>>4)*4 + i];
  }
  const size_t gbase = ((size_t)(b0 + w))*((size_t)NT*DD) + lane;
  float rx = X[gbase], rm = Mm[gbase], rl = Ll[gbase];
  write_x(FRu, 1, w, lane, rx*rm + rl*(1.0f - rm));
  rx = X[gbase + DD]; rm = Mm[gbase + DD]; rl = Ll[gbase + DD];
  __syncthreads();

  for (int s = 0; s < NSTEP_FB; ++s) {
    const int par = s & 1, rp = par ^ 1;
    float nx = 0.f, nm = 0.f, nl = 0.f;
    if (s <= 509) { size_t g = gbase + (size_t)(s+2)*DD; nx = X[g]; nm = Mm[g]; nl = Ll[g]; }
    if (s >= 5) {
      s16x8 bh_, bl_;
      read_b(FRu + rp*PSTRIDE + H4C, lane, bh_, bl_);
      const int bb = lane & 15, q = lane >> 4;
#pragma unroll
      for (int t4 = 0; t4 < 4; ++t4) {
        f32x4 a_ = cO[t4];
        a_ = MFMA16(Oh[t4], bh_, a_); a_ = MFMA16(Oh[t4], bl_, a_); a_ = MFMA16(Ol[t4], bh_, a_);
        if (bb < 8) {
#pragma unroll
          for (int i = 0; i < 4; ++i) OST[bb*65 + t4*16 + q*4 + i] = a_[i];
        }
      }
    }
    __syncthreads();
    if (s >= 5)
      out[((size_t)(b0 + w)*NT + (s-5))*DD + lane] = OST[w*65 + lane];
    if (s <= 510) write_x(FRu, par, w, lane, rx*rm + rl*(1.0f - rm));
    rx = nx; rm = nm; rl = nl;
    __syncthreads();
  }
}

__global__ __launch_bounds__(NTH, 1)
void gru_mfma(const float* __restrict__ X, const float* __restrict__ M, const float* __restrict__ L,
              const float* __restrict__ wih0, const float* __restrict__ whh0, const float* __restrict__ bih0, const float* __restrict__ bhh0,
              const float* __restrict__ wih1, const float* __restrict__ whh1, const float* __restrict__ bih1, const float* __restrict__ bhh1,
              const float* __restrict__ wih2, const float* __restrict__ whh2, const float* __restrict__ bih2, const float* __restrict__ bhh2,
              const float* __restrict__ wih3, const float* __restrict__ whh3, const float* __restrict__ bih3, const float* __restrict__ bhh3,
              const float* __restrict__ wih4, const float* __restrict__ whh4, const float* __restrict__ bih4, const float* __restrict__ bhh4,
              const float* __restrict__ out_w, const float* __restrict__ out_b,
              float* __restrict__ out)
{
  __shared__ __align__(16) u16 FRu[FRTOT];
  __shared__ float OST[8*65];
  const int tid = threadIdx.x;
  const int w = tid >> 6, lane = tid & 63;
  const int b0 = blockIdx.x * 8;

  for (int i = tid; i < FRTOT; i += NTH) FRu[i] = 0;
  for (int i = tid; i < 8*65; i += NTH) OST[i] = 0.f;
  __syncthreads();

  if (w == 0)
    wave_gru_fb<64,32,2>(wih0,whh0,bih0,bhh0,  0, XIN0, H0C, 0, 511, FRu, OST, X,M,L, out, b0, w, lane);
  else if (w == 1)
    wave_gru_fb<64,32,2>(wih0,whh0,bih0,bhh0, 16, XIN0, H0C, 0, 511, FRu, OST, X,M,L, out, b0, w, lane);
  else if (w == 2)
    wave_gru_fb<32,16,1>(wih1,whh1,bih1,bhh1,  0, H0C,  H1C, 1, 512, FRu, OST, X,M,L, out, b0, w, lane);
  else if (w == 4)
    wave_gru_fb<16, 8,1>(wih2,whh2,bih2,bhh2,  0, H1C,  H2C, 2, 513, FRu, OST, X,M,L, out, b0, w, lane);
  else if (w == 5)
    wave_gru_fb< 8,16,1>(wih3,whh3,bih3,bhh3,  0, H2C,  H3C, 3, 514, FRu, OST, X,M,L, out, b0, w, lane);
  else if (w == 3)
    wave_gru_fb<16,32,1>(wih4,whh4,bih4,bhh4,  0, H3C,  H4C, 4, 515, FRu, OST, X,M,L, out, b0, w, lane);
  else if (w == 6)
    wave_gru_fb<16,32,1>(wih4,whh4,bih4,bhh4, 16, H3C,  H4C, 4, 515, FRu, OST, X,M,L, out, b0, w, lane);
  else
    wave_out_fb(out_w, out_b, FRu, OST, X,M,L, out, b0, w, lane);
}

extern "C" void kernel_launch(void* const* d_in, const int* in_sizes, int n_in,
                              void* d_out, int out_size, void* d_ws, size_t ws_size,
                              hipStream_t stream)
{
  const float* X  = (const float*)d_in[0];
  const float* M  = (const float*)d_in[1];
  const float* L  = (const float*)d_in[2];
  const float* wp[20];
  for (int i = 0; i < 20; ++i) wp[i] = (const float*)d_in[3 + i];
  const float* ow = (const float*)d_in[23];
  const float* ob = (const float*)d_in[24];
  float* out = (float*)d_out;

  const size_t gi_bytes = (size_t)2048 * NT * 96 * sizeof(float);  // 402,653,184
  if (ws_size >= gi_bytes) {
    float* gi = (float*)d_ws;
    gi0_gemm<<<dim3(2048*4), dim3(256), 0, stream>>>(X, M, L, wp[0], wp[2], wp[3], gi);
    // 128 KB dynamic LDS > 64 KB default cap
    hipFuncSetAttribute((const void*)gru_rec_t4, hipFuncAttributeMaxDynamicSharedMemorySize, LDS3_BYTES);
    gru_rec_t4<<<dim3(2048 / BB), dim3(NTH), LDS3_BYTES, stream>>>(
        gi, wp[1], wp[3],
        wp[4], wp[5], wp[6], wp[7],
        wp[8], wp[9], wp[10], wp[11],
        wp[12], wp[13], wp[14], wp[15],
        wp[16], wp[17], wp[18], wp[19],
        ow, ob, out);
  } else {
    gru_mfma<<<dim3(2048 / BB), dim3(NTH), 0, stream>>>(
        X, M, L,
        wp[0], wp[1], wp[2], wp[3],
        wp[4], wp[5], wp[6], wp[7],
        wp[8], wp[9], wp[10], wp[11],
        wp[12], wp[13], wp[14], wp[15],
        wp[16], wp[17], wp[18], wp[19],
        ow, ob, out);
  }
}